// Round 8
// baseline (1708.090 us; speedup 1.0000x reference)
//
#include <hip/hip_runtime.h>
#include <hip/hip_fp16.h>
#include <hip/hip_cooperative_groups.h>

namespace cg = cooperative_groups;

#define IDIM 512
#define HDIM 512
#define NGATE 2048
#define SEGS 128
#define BATCH 64
#define ZK 0.1f

typedef _Float16 f16;
typedef _Float16 f16x8 __attribute__((ext_vector_type(8)));
typedef float f32x4 __attribute__((ext_vector_type(4)));

__device__ __forceinline__ void gload16(const void* g, void* l) {
  __builtin_amdgcn_global_load_lds((const __attribute__((address_space(1))) void*)g,
                                   (__attribute__((address_space(3))) void*)l, 16, 0, 0);
}
__device__ __forceinline__ float sigmoidf_(float x) { return 1.0f / (1.0f + __expf(-x)); }
__device__ __forceinline__ float tanhf_(float x) { return 2.0f / (1.0f + __expf(-2.0f * x)) - 1.0f; }

// ---------------- prep: starts, counting-sort by dur desc, Mk, mel_len ----------------
__global__ void prep_kernel(const int* __restrict__ durs, int4* __restrict__ meta,
                            int* __restrict__ Mk, int* __restrict__ mel) {
  __shared__ int hist[16];
  __shared__ int cur[16];
  int tid = threadIdx.x;  // 64 threads, one per batch element
  if (tid < 16) hist[tid] = 0;
  __syncthreads();
  int b = tid;
  for (int s = 0; s < SEGS; ++s) atomicAdd(&hist[durs[s * BATCH + b] & 15], 1);
  __syncthreads();
  if (tid == 0) {
    int run = 0;
    for (int d = 15; d >= 0; --d) { cur[d] = run; run += hist[d]; }
    for (int kk = 0; kk < 12; ++kk) Mk[kk] = cur[kk];
  }
  __syncthreads();
  int run = 0;
  for (int s = 0; s < SEGS; ++s) {
    int d = durs[s * BATCH + b] & 15;
    int pos = atomicAdd(&cur[d], 1);
    meta[pos] = make_int4(run, b, s, d);  // start, b, s, dur
    run += d;
  }
  mel[b] = run;
}

// ---------------- W prep: permuted combined weight (fp16) + bias ----------------
__global__ void wprep_kernel(const float* __restrict__ Wih, const float* __restrict__ Whh,
                             const float* __restrict__ bih, const float* __restrict__ bhh,
                             f16* __restrict__ Wc, float* __restrict__ biasp) {
  int n = blockIdx.x;
  int G = n >> 6, q = (n >> 4) & 3, r = n & 15;
  int j = G * 16 + r;
  int orig = q * 512 + j;
  for (int kk = threadIdx.x; kk < 1024; kk += blockDim.x) {
    float v = (kk < 512) ? Wih[(size_t)orig * 512 + kk] : Whh[(size_t)orig * 512 + kk - 512];
    Wc[(size_t)n * 1024 + kk] = (f16)v;
  }
  if (threadIdx.x == 0) biasp[n] = bih[orig] + bhh[orig];
}

// ---------------- x: fp32 -> fp16 ----------------
__global__ void xconv_kernel(const float* __restrict__ x, f16* __restrict__ xh, long n8) {
  long i = (long)blockIdx.x * blockDim.x + threadIdx.x;
  long stride = (long)gridDim.x * blockDim.x;
  for (; i < n8; i += stride) {
    const float4* p = (const float4*)(x + i * 8);
    float4 a = p[0], bv = p[1];
    f16x8 o;
    o[0] = (f16)a.x;  o[1] = (f16)a.y;  o[2] = (f16)a.z;  o[3] = (f16)a.w;
    o[4] = (f16)bv.x; o[5] = (f16)bv.y; o[6] = (f16)bv.z; o[7] = (f16)bv.w;
    *(f16x8*)(xh + i * 8) = o;
  }
}

// ---------------- zero invalid output rows + h + c (grid-stride) ----------------
__global__ void zero_kernel(float* __restrict__ out, const int* __restrict__ mel,
                            int T, int total) {
  int tb = T * BATCH;
  for (int bid = blockIdx.x; bid < total; bid += gridDim.x) {
    if (bid < tb) {
      int t = bid / BATCH, b = bid - t * BATCH;
      if (t < mel[b]) continue;
      float4* p = (float4*)(out + (size_t)bid * HDIM);
      p[threadIdx.x] = make_float4(0.f, 0.f, 0.f, 0.f);
    } else {
      int e = bid - tb;
      float4* p = (float4*)(out + (size_t)tb * HDIM + (size_t)e * HDIM);
      p[threadIdx.x] = make_float4(0.f, 0.f, 0.f, 0.f);
    }
  }
}

// ============ PERSISTENT: all 12 steps in one cooperative kernel ============
// 256 blocks x 512 threads (1 block/CU), grid.sync() between steps.
// Per step: block bid takes tile (by=bid>>3, bx=bid&7) of the 256^2 tiling;
// GEMM core = round-3 proven 8-wave depth-2 counted-vmcnt structure.
__global__ __launch_bounds__(512, 1)
void persist_kernel(const f16* __restrict__ xh, const f16* __restrict__ Wc,
                    const float* __restrict__ biasp,
                    f16* __restrict__ hst0, f16* __restrict__ hst1,
                    float* __restrict__ cst,
                    const int4* __restrict__ meta, const int* __restrict__ Mk,
                    float* __restrict__ out, int T) {
  cg::grid_group grid = cg::this_grid();

  __shared__ __align__(16) f16 As[2][256][64];
  __shared__ __align__(16) f16 Bs[2][256][64];
  __shared__ int4 metaS[256];

  const int bid = blockIdx.x;
  const int tid = threadIdx.x;
  const int lane = tid & 63;
  const int w = tid >> 6;          // 0..7
  const int wr = w >> 2;           // 0..1 : rows wr*128..+128
  const int wc = w & 3;            // 0..3 : cols wc*64..+64
  const int lr = lane & 15;
  const int lk = lane >> 4;        // 0..3
  const int swzc = (((lane & 7) ^ ((lane >> 3) & 7)) << 3);
  const size_t segoff = (size_t)T * BATCH * HDIM + (size_t)2 * BATCH * HDIM;

  for (int k = 0; k < 12; ++k) {
    const int mk = Mk[k];
    const int npan = (mk + 255) >> 8;
    const int ntiles = npan * 8;
    const f16* hprev = (k & 1) ? hst1 : hst0;
    f16* hnext = (k & 1) ? hst0 : hst1;

    if (bid < ntiles) {
      const int by = bid >> 3, bx = bid & 7;
      const int m0 = by * 256;
      const int n0 = bx * 256;

      if (tid < 256) metaS[tid] = meta[m0 + tid];

      // --- per-tile staging setup ---
      size_t xoff[4];
      int ra4[4];
#pragma unroll
      for (int o = 0; o < 4; ++o) {
        int trow = o * 64 + w * 8 + (lane >> 3);
        int r = m0 + trow;
        int ra = (r < mk) ? r : 0;  // dead rows stage row 0 (masked in epilogue)
        int4 mt = meta[ra];
        xoff[o] = ((size_t)(mt.x + k) * BATCH + mt.y) * IDIM + swzc;
        ra4[o] = ra;
      }

      auto stageA = [&](int o, int kb, int slot) {
        const f16* src;
        if (k == 0 || kb < 8) src = xh + xoff[o] + kb * 64;
        else src = hprev + (size_t)ra4[o] * HDIM + (kb - 8) * 64 + swzc;
        gload16(src, &As[slot][o * 64 + w * 8][0]);
      };
      auto stageB = [&](int o, int kb, int slot) {
        int trow = o * 64 + w * 8 + (lane >> 3);
        gload16(Wc + (size_t)(n0 + trow) * 1024 + (size_t)kb * 64 + swzc,
                &Bs[slot][o * 64 + w * 8][0]);
      };
      auto lda = [&](int slot, int h, int f, int ks) -> f16x8 {
        int row = wr * 128 + h * 64 + f * 16 + lr;
        int ch = (((ks * 4 + lk) ^ (lr & 7)) << 3);
        return *(const f16x8*)&As[slot][row][ch];
      };
      auto ldb = [&](int slot, int q, int ks) -> f16x8 {
        int row = wc * 64 + q * 16 + lr;
        int ch = (((ks * 4 + lk) ^ (lr & 7)) << 3);
        return *(const f16x8*)&Bs[slot][row][ch];
      };

      f32x4 acc[8][4];
#pragma unroll
      for (int a = 0; a < 8; ++a)
#pragma unroll
        for (int bb = 0; bb < 4; ++bb) acc[a][bb] = (f32x4){0.f, 0.f, 0.f, 0.f};

      const int KB = (k == 0) ? 8 : 16;

      // prologue: prime tiles 0 (slot 0) and 1 (slot 1); counted wait
#pragma unroll
      for (int o = 0; o < 4; ++o) stageA(o, 0, 0);
#pragma unroll
      for (int o = 0; o < 4; ++o) stageB(o, 0, 0);
#pragma unroll
      for (int o = 0; o < 4; ++o) stageA(o, 1, 1);
#pragma unroll
      for (int o = 0; o < 4; ++o) stageB(o, 1, 1);
      asm volatile("s_waitcnt vmcnt(8)" ::: "memory");
      __builtin_amdgcn_s_barrier();

      f16x8 aF[4][2], bF[4][2];

      for (int kt = 0; kt < KB; ++kt) {
        const int s = kt & 1;
        const bool st1 = (kt + 1 < KB);
        const bool st2 = (kt + 2 < KB);

        // ---- phase 0: read all B + A-half0 fragments; MFMA (h0, fn0-1) ----
#pragma unroll
        for (int f = 0; f < 4; ++f)
#pragma unroll
          for (int ks = 0; ks < 2; ++ks) aF[f][ks] = lda(s, 0, f, ks);
#pragma unroll
        for (int q = 0; q < 4; ++q)
#pragma unroll
          for (int ks = 0; ks < 2; ++ks) bF[q][ks] = ldb(s, q, ks);
        __builtin_amdgcn_s_barrier();
        __builtin_amdgcn_s_setprio(1);
#pragma unroll
        for (int f = 0; f < 4; ++f)
#pragma unroll
          for (int fn = 0; fn < 2; ++fn)
#pragma unroll
            for (int ks = 0; ks < 2; ++ks)
              acc[f][fn] = __builtin_amdgcn_mfma_f32_16x16x32_f16(aF[f][ks], bF[fn][ks], acc[f][fn], 0, 0, 0);
        __builtin_amdgcn_s_setprio(0);
        __builtin_amdgcn_s_barrier();

        // ---- phase 1: stage B(kt+2) -> B[s]; MFMA (h0, fn2-3) ----
        if (st2) {
#pragma unroll
          for (int o = 0; o < 4; ++o) stageB(o, kt + 2, s);
        }
        __builtin_amdgcn_s_barrier();
        __builtin_amdgcn_s_setprio(1);
#pragma unroll
        for (int f = 0; f < 4; ++f)
#pragma unroll
          for (int fn = 2; fn < 4; ++fn)
#pragma unroll
            for (int ks = 0; ks < 2; ++ks)
              acc[f][fn] = __builtin_amdgcn_mfma_f32_16x16x32_f16(aF[f][ks], bF[fn][ks], acc[f][fn], 0, 0, 0);
        __builtin_amdgcn_s_setprio(0);
        __builtin_amdgcn_s_barrier();

        // ---- phase 2: read A-half1; stage A(kt+2) ops 0,2; MFMA (h1, fn0-1) ----
#pragma unroll
        for (int f = 0; f < 4; ++f)
#pragma unroll
          for (int ks = 0; ks < 2; ++ks) aF[f][ks] = lda(s, 1, f, ks);
        if (st2) { stageA(0, kt + 2, s); stageA(2, kt + 2, s); }
        __builtin_amdgcn_s_barrier();
        __builtin_amdgcn_s_setprio(1);
#pragma unroll
        for (int f = 0; f < 4; ++f)
#pragma unroll
          for (int fn = 0; fn < 2; ++fn)
#pragma unroll
            for (int ks = 0; ks < 2; ++ks)
              acc[4 + f][fn] = __builtin_amdgcn_mfma_f32_16x16x32_f16(aF[f][ks], bF[fn][ks], acc[4 + f][fn], 0, 0, 0);
        __builtin_amdgcn_s_setprio(0);
        __builtin_amdgcn_s_barrier();

        // ---- phase 3: stage A(kt+2) ops 1,3; MFMA (h1, fn2-3); counted wait ----
        if (st2) { stageA(1, kt + 2, s); stageA(3, kt + 2, s); }
        __builtin_amdgcn_s_setprio(1);
#pragma unroll
        for (int f = 0; f < 4; ++f)
#pragma unroll
          for (int fn = 2; fn < 4; ++fn)
#pragma unroll
            for (int ks = 0; ks < 2; ++ks)
              acc[4 + f][fn] = __builtin_amdgcn_mfma_f32_16x16x32_f16(aF[f][ks], bF[fn][ks], acc[4 + f][fn], 0, 0, 0);
        __builtin_amdgcn_s_setprio(0);
        if (st2) {
          asm volatile("s_waitcnt vmcnt(8)" ::: "memory");
        } else if (st1) {
          asm volatile("s_waitcnt vmcnt(0)" ::: "memory");
        }
        __builtin_amdgcn_s_barrier();
      }

      // ---- fused LSTM epilogue ----
      float bq[4];
#pragma unroll
      for (int q = 0; q < 4; ++q) bq[q] = biasp[n0 + wc * 64 + q * 16 + lr];
      const int j = ((n0 + wc * 64) >> 6) * 16 + lr;

#pragma unroll
      for (int fm = 0; fm < 8; ++fm) {
#pragma unroll
        for (int reg = 0; reg < 4; ++reg) {
          int m = m0 + wr * 128 + fm * 16 + ((lane >> 4) << 2) + reg;
          if (m >= mk) continue;
          int4 mt = metaS[m - m0];
          float gi = acc[fm][0][reg] + bq[0];
          float gf = acc[fm][1][reg] + bq[1];
          float gg = acc[fm][2][reg] + bq[2];
          float go = acc[fm][3][reg] + bq[3];
          float iv = sigmoidf_(gi), fv = sigmoidf_(gf);
          float gv = tanhf_(gg), ov = sigmoidf_(go);
          float cp, hp;
          if (k == 0) { cp = 0.f; hp = 0.f; }
          else {
            cp = cst[(size_t)m * HDIM + j];
            hp = (float)hprev[(size_t)m * HDIM + j];
          }
          float cn = fv * cp + iv * gv;
          float hn = ov * tanhf_(cn);
          float hz = ZK * hp + (1.f - ZK) * hn;
          float cz = ZK * cp + (1.f - ZK) * cn;
          out[((size_t)(mt.x + k) * BATCH + mt.y) * HDIM + j] = hz;
          if (k == mt.w - 1) {
            out[segoff + ((size_t)mt.y * SEGS + mt.z) * HDIM + j] = hz;
          } else {
            hnext[(size_t)m * HDIM + j] = (f16)hz;
            cst[(size_t)m * HDIM + j] = cz;
          }
        }
      }
    }

    if (k < 11) grid.sync();
  }
}

extern "C" void kernel_launch(void* const* d_in, const int* in_sizes, int n_in,
                              void* d_out, int out_size, void* d_ws, size_t ws_size,
                              hipStream_t stream) {
  const float* x = (const float*)d_in[0];
  const int* durs = (const int*)d_in[1];
  const float* Wih = (const float*)d_in[2];
  const float* Whh = (const float*)d_in[3];
  const float* bih = (const float*)d_in[4];
  const float* bhh = (const float*)d_in[5];
  float* out = (float*)d_out;
  int T = in_sizes[0] / (BATCH * IDIM);

  char* ws = (char*)d_ws;
  size_t off = 0;
  auto alloc = [&](size_t bytes) {
    void* p = ws + off;
    off = (off + bytes + 255) & ~(size_t)255;
    return p;
  };
  f16* xh     = (f16*)alloc((size_t)T * BATCH * IDIM * 2);
  f16* Wc     = (f16*)alloc((size_t)NGATE * 1024 * 2);
  float* biasp= (float*)alloc((size_t)NGATE * 4);
  f16* hst0   = (f16*)alloc((size_t)SEGS * BATCH * HDIM * 2);
  f16* hst1   = (f16*)alloc((size_t)SEGS * BATCH * HDIM * 2);
  float* cst  = (float*)alloc((size_t)SEGS * BATCH * HDIM * 4);
  int4* meta  = (int4*)alloc((size_t)SEGS * BATCH * 16);
  int* Mk     = (int*)alloc(64);
  int* mel    = (int*)alloc(64);

  prep_kernel<<<1, 64, 0, stream>>>(durs, meta, Mk, mel);
  wprep_kernel<<<NGATE, 256, 0, stream>>>(Wih, Whh, bih, bhh, Wc, biasp);
  long n8 = (long)T * BATCH * IDIM / 8;
  xconv_kernel<<<2048, 256, 0, stream>>>(x, xh, n8);
  zero_kernel<<<2048, 128, 0, stream>>>(out, mel, T, T * BATCH + 128);

  // all 12 steps in one cooperative persistent kernel (256 blocks = 1/CU)
  void* kargs[] = {(void*)&xh, (void*)&Wc, (void*)&biasp, (void*)&hst0, (void*)&hst1,
                   (void*)&cst, (void*)&meta, (void*)&Mk, (void*)&out, (void*)&T};
  hipLaunchCooperativeKernel((const void*)persist_kernel, dim3(256), dim3(512),
                             kargs, 0, stream);
}

// Round 9
// 1013.454 us; speedup vs baseline: 1.6854x; 1.6854x over previous
//
#include <hip/hip_runtime.h>
#include <hip/hip_fp16.h>

#define IDIM 512
#define HDIM 512
#define NGATE 2048
#define SEGS 128
#define BATCH 64
#define ZK 0.1f

typedef _Float16 f16;
typedef _Float16 f16x8 __attribute__((ext_vector_type(8)));
typedef float f32x4 __attribute__((ext_vector_type(4)));

__device__ __forceinline__ void gload16(const void* g, void* l) {
  __builtin_amdgcn_global_load_lds((const __attribute__((address_space(1))) void*)g,
                                   (__attribute__((address_space(3))) void*)l, 16, 0, 0);
}
__device__ __forceinline__ float sigmoidf_(float x) { return 1.0f / (1.0f + __expf(-x)); }
__device__ __forceinline__ float tanhf_(float x) { return 2.0f / (1.0f + __expf(-2.0f * x)) - 1.0f; }

// ---------------- prep: starts, counting-sort by dur desc, Mk, mel_len ----------------
__global__ void prep_kernel(const int* __restrict__ durs, int4* __restrict__ meta,
                            int* __restrict__ Mk, int* __restrict__ mel) {
  __shared__ int hist[16];
  __shared__ int cur[16];
  int tid = threadIdx.x;  // 64 threads, one per batch element
  if (tid < 16) hist[tid] = 0;
  __syncthreads();
  int b = tid;
  for (int s = 0; s < SEGS; ++s) atomicAdd(&hist[durs[s * BATCH + b] & 15], 1);
  __syncthreads();
  if (tid == 0) {
    int run = 0;
    for (int d = 15; d >= 0; --d) { cur[d] = run; run += hist[d]; }
    for (int kk = 0; kk < 12; ++kk) Mk[kk] = cur[kk];
  }
  __syncthreads();
  int run = 0;
  for (int s = 0; s < SEGS; ++s) {
    int d = durs[s * BATCH + b] & 15;
    int pos = atomicAdd(&cur[d], 1);
    meta[pos] = make_int4(run, b, s, d);  // start, b, s, dur
    run += d;
  }
  mel[b] = run;
}

// ---------------- W prep: permuted combined weight (fp16) + bias ----------------
__global__ void wprep_kernel(const float* __restrict__ Wih, const float* __restrict__ Whh,
                             const float* __restrict__ bih, const float* __restrict__ bhh,
                             f16* __restrict__ Wc, float* __restrict__ biasp) {
  int n = blockIdx.x;
  int G = n >> 6, q = (n >> 4) & 3, r = n & 15;
  int j = G * 16 + r;
  int orig = q * 512 + j;
  for (int kk = threadIdx.x; kk < 1024; kk += blockDim.x) {
    float v = (kk < 512) ? Wih[(size_t)orig * 512 + kk] : Whh[(size_t)orig * 512 + kk - 512];
    Wc[(size_t)n * 1024 + kk] = (f16)v;
  }
  if (threadIdx.x == 0) biasp[n] = bih[orig] + bhh[orig];
}

// ---------------- x: fp32 -> fp16 ----------------
__global__ void xconv_kernel(const float* __restrict__ x, f16* __restrict__ xh, long n8) {
  long i = (long)blockIdx.x * blockDim.x + threadIdx.x;
  long stride = (long)gridDim.x * blockDim.x;
  for (; i < n8; i += stride) {
    const float4* p = (const float4*)(x + i * 8);
    float4 a = p[0], bv = p[1];
    f16x8 o;
    o[0] = (f16)a.x;  o[1] = (f16)a.y;  o[2] = (f16)a.z;  o[3] = (f16)a.w;
    o[4] = (f16)bv.x; o[5] = (f16)bv.y; o[6] = (f16)bv.z; o[7] = (f16)bv.w;
    *(f16x8*)(xh + i * 8) = o;
  }
}

// ---------------- zero invalid output rows + h + c (grid-stride) ----------------
__global__ void zero_kernel(float* __restrict__ out, const int* __restrict__ mel,
                            int T, int total) {
  int tb = T * BATCH;
  for (int bid = blockIdx.x; bid < total; bid += gridDim.x) {
    if (bid < tb) {
      int t = bid / BATCH, b = bid - t * BATCH;
      if (t < mel[b]) continue;
      float4* p = (float4*)(out + (size_t)bid * HDIM);
      p[threadIdx.x] = make_float4(0.f, 0.f, 0.f, 0.f);
    } else {
      int e = bid - tb;
      float4* p = (float4*)(out + (size_t)tb * HDIM + (size_t)e * HDIM);
      p[threadIdx.x] = make_float4(0.f, 0.f, 0.f, 0.f);
    }
  }
}

// ============ HEAD: 256x256, 8 waves, m201-style 8-phase / 2 K-tiles ============
// Per iteration (2 K-tiles, slots 0/1 fixed): 8 phases of {ds_read next-quadrant frags
// | stage | barrier | setprio+16 MFMA+setprio | barrier}; vmcnt(4) at end-P1/P5 only.
template <bool FIRST>
__global__ __launch_bounds__(512, 1)
void step256_kernel(const f16* __restrict__ xh, const f16* __restrict__ Wc,
                    const float* __restrict__ biasp,
                    const f16* __restrict__ hprev, f16* __restrict__ hnext,
                    float* __restrict__ cst,
                    const int4* __restrict__ meta, const int* __restrict__ Mk,
                    float* __restrict__ out, int T, int k) {
  const int mk = Mk[k];
  // bijective chunked XCD swizzle (round-3 form; nwg=256, %8==0)
  const int nbx = gridDim.x;
  const int orig = blockIdx.y * nbx + blockIdx.x;
  const int swz = (orig & 7) * 32 + (orig >> 3);
  const int by = swz / nbx, bx = swz - by * nbx;
  const int m0 = by * 256;
  if (m0 >= mk) return;
  const int n0 = bx * 256;

  __shared__ __align__(16) f16 As[2][256][64];
  __shared__ __align__(16) f16 Bs[2][256][64];
  __shared__ int4 metaS[256];

  const int tid = threadIdx.x;
  const int lane = tid & 63;
  const int w = tid >> 6;          // 0..7
  const int wr = w >> 2;           // 0..1 : rows wr*128..+128
  const int wc = w & 3;            // 0..3 : cols wc*64..+64
  const int lr = lane & 15;
  const int lk = lane >> 4;        // 0..3

  if (tid < 256) metaS[tid] = meta[m0 + tid];

  // --- staging setup: per-lane gathered sources, pre-swizzled column chunk ---
  const int swzc = (((lane & 7) ^ ((lane >> 3) & 7)) << 3);
  size_t xoff[4];
  int ra4[4];
#pragma unroll
  for (int o = 0; o < 4; ++o) {
    int trow = o * 64 + w * 8 + (lane >> 3);
    int r = m0 + trow;
    int ra = (r < mk) ? r : 0;  // dead rows stage row 0 (masked in epilogue)
    int4 mt = meta[ra];
    xoff[o] = ((size_t)(mt.x + k) * BATCH + mt.y) * IDIM + swzc;
    ra4[o] = ra;
  }

  auto stageA = [&](int o, int kb, int slot) {
    const f16* src;
    if (FIRST || kb < 8) src = xh + xoff[o] + kb * 64;
    else src = hprev + (size_t)ra4[o] * HDIM + (kb - 8) * 64 + swzc;
    gload16(src, &As[slot][o * 64 + w * 8][0]);
  };
  auto stageB = [&](int o, int kb, int slot) {
    int trow = o * 64 + w * 8 + (lane >> 3);
    gload16(Wc + (size_t)(n0 + trow) * 1024 + (size_t)kb * 64 + swzc,
            &Bs[slot][o * 64 + w * 8][0]);
  };
  auto lda = [&](int slot, int h, int f, int ks) -> f16x8 {
    int row = wr * 128 + h * 64 + f * 16 + lr;
    int ch = (((ks * 4 + lk) ^ (lr & 7)) << 3);
    return *(const f16x8*)&As[slot][row][ch];
  };
  auto ldb = [&](int slot, int q, int ks) -> f16x8 {
    int row = wc * 64 + q * 16 + lr;
    int ch = (((ks * 4 + lk) ^ (lr & 7)) << 3);
    return *(const f16x8*)&Bs[slot][row][ch];
  };

  f32x4 acc[8][4];
#pragma unroll
  for (int a = 0; a < 8; ++a)
#pragma unroll
    for (int bb = 0; bb < 4; ++bb) acc[a][bb] = (f32x4){0.f, 0.f, 0.f, 0.f};

  const int KB = FIRST ? 8 : 16;
  const int NITER = KB >> 1;

  // prologue: prime K-tiles 0 (slot0) and 1 (slot1); counted wait; pre-read P7-style frags
#pragma unroll
  for (int o = 0; o < 4; ++o) stageA(o, 0, 0);
#pragma unroll
  for (int o = 0; o < 4; ++o) stageB(o, 0, 0);
#pragma unroll
  for (int o = 0; o < 4; ++o) stageA(o, 1, 1);
#pragma unroll
  for (int o = 0; o < 4; ++o) stageB(o, 1, 1);
  asm volatile("s_waitcnt vmcnt(8)" ::: "memory");  // tile 0 landed; tile 1 in flight
  __builtin_amdgcn_s_barrier();

  f16x8 aF0[4][2], aF1[4][2], aN0[4][2], aN1[4][2];
  f16x8 bA[2][2], bB[2][2], bC[2][2], bD[2][2];

  // prologue reads (= P7 of a virtual previous iteration): aF0, bA from slot0
#pragma unroll
  for (int f = 0; f < 4; ++f)
#pragma unroll
    for (int ks = 0; ks < 2; ++ks) aF0[f][ks] = lda(0, 0, f, ks);
#pragma unroll
  for (int q = 0; q < 2; ++q)
#pragma unroll
    for (int ks = 0; ks < 2; ++ks) bA[q][ks] = ldb(0, q, ks);

#define MFMA_Q(ACC_R, ACC_C, AFR, BFR)                                              \
  __builtin_amdgcn_s_setprio(1);                                                    \
  _Pragma("unroll") for (int f = 0; f < 4; ++f)                                     \
    _Pragma("unroll") for (int q = 0; q < 2; ++q)                                   \
      _Pragma("unroll") for (int ks = 0; ks < 2; ++ks)                              \
        acc[ACC_R + f][ACC_C + q] =                                                 \
            __builtin_amdgcn_mfma_f32_16x16x32_f16(AFR[f][ks], BFR[q][ks],          \
                                                   acc[ACC_R + f][ACC_C + q], 0, 0, 0); \
  __builtin_amdgcn_s_setprio(0);

  for (int i = 0; i < NITER; ++i) {
    const int kt0 = 2 * i;
    const bool st = (i + 1 < NITER);

    // ---- P0: read bB (B slot0 fn2-3); MFMA Q0(t0) ----
#pragma unroll
    for (int q = 0; q < 2; ++q)
#pragma unroll
      for (int ks = 0; ks < 2; ++ks) bB[q][ks] = ldb(0, q + 2, ks);
    __builtin_amdgcn_s_barrier();
    MFMA_Q(0, 0, aF0, bA)
    __builtin_amdgcn_s_barrier();

    // ---- P1: read aF1 (A slot0 h1); stage B(kt0+2)->s0B; MFMA Q1(t0); vmcnt ----
#pragma unroll
    for (int f = 0; f < 4; ++f)
#pragma unroll
      for (int ks = 0; ks < 2; ++ks) aF1[f][ks] = lda(0, 1, f, ks);
    if (st) {
#pragma unroll
      for (int o = 0; o < 4; ++o) stageB(o, kt0 + 2, 0);
    }
    __builtin_amdgcn_s_barrier();
    MFMA_Q(0, 2, aF0, bB)
    if (st) { asm volatile("s_waitcnt vmcnt(4)" ::: "memory"); }
    else    { asm volatile("s_waitcnt vmcnt(0)" ::: "memory"); }
    __builtin_amdgcn_s_barrier();

    // ---- P2: stage A(kt0+2)->s0A; MFMA Q2(t0) ----
    if (st) {
#pragma unroll
      for (int o = 0; o < 4; ++o) stageA(o, kt0 + 2, 0);
    }
    __builtin_amdgcn_s_barrier();
    MFMA_Q(4, 0, aF1, bA)
    __builtin_amdgcn_s_barrier();

    // ---- P3: read aN0 (A slot1 h0) + bC (B slot1 fn0-1); MFMA Q3(t0) ----
#pragma unroll
    for (int f = 0; f < 4; ++f)
#pragma unroll
      for (int ks = 0; ks < 2; ++ks) aN0[f][ks] = lda(1, 0, f, ks);
#pragma unroll
    for (int q = 0; q < 2; ++q)
#pragma unroll
      for (int ks = 0; ks < 2; ++ks) bC[q][ks] = ldb(1, q, ks);
    __builtin_amdgcn_s_barrier();
    MFMA_Q(4, 2, aF1, bB)
    __builtin_amdgcn_s_barrier();

    // ---- P4: read bD (B slot1 fn2-3); MFMA Q0(t1) ----
#pragma unroll
    for (int q = 0; q < 2; ++q)
#pragma unroll
      for (int ks = 0; ks < 2; ++ks) bD[q][ks] = ldb(1, q + 2, ks);
    __builtin_amdgcn_s_barrier();
    MFMA_Q(0, 0, aN0, bC)
    __builtin_amdgcn_s_barrier();

    // ---- P5: read aN1 (A slot1 h1); stage B(kt0+3)->s1B; MFMA Q1(t1); vmcnt ----
#pragma unroll
    for (int f = 0; f < 4; ++f)
#pragma unroll
      for (int ks = 0; ks < 2; ++ks) aN1[f][ks] = lda(1, 1, f, ks);
    if (st) {
#pragma unroll
      for (int o = 0; o < 4; ++o) stageB(o, kt0 + 3, 1);
    }
    __builtin_amdgcn_s_barrier();
    MFMA_Q(0, 2, aN0, bD)
    if (st) { asm volatile("s_waitcnt vmcnt(4)" ::: "memory"); }
    __builtin_amdgcn_s_barrier();

    // ---- P6: stage A(kt0+3)->s1A; MFMA Q2(t1) ----
    if (st) {
#pragma unroll
      for (int o = 0; o < 4; ++o) stageA(o, kt0 + 3, 1);
    }
    __builtin_amdgcn_s_barrier();
    MFMA_Q(4, 0, aN1, bC)
    __builtin_amdgcn_s_barrier();

    // ---- P7: read next-iter aF0,bA from slot0; MFMA Q3(t1) ----
    if (st) {
#pragma unroll
      for (int f = 0; f < 4; ++f)
#pragma unroll
        for (int ks = 0; ks < 2; ++ks) aF0[f][ks] = lda(0, 0, f, ks);
#pragma unroll
      for (int q = 0; q < 2; ++q)
#pragma unroll
        for (int ks = 0; ks < 2; ++ks) bA[q][ks] = ldb(0, q, ks);
    }
    __builtin_amdgcn_s_barrier();
    MFMA_Q(4, 2, aN1, bD)
    __builtin_amdgcn_s_barrier();
  }
#undef MFMA_Q

  // ---- fused LSTM epilogue ----
  float bq[4];
#pragma unroll
  for (int q = 0; q < 4; ++q) bq[q] = biasp[n0 + wc * 64 + q * 16 + lr];
  const int j = ((n0 + wc * 64) >> 6) * 16 + lr;
  const size_t segoff = (size_t)T * BATCH * HDIM + (size_t)2 * BATCH * HDIM;

#pragma unroll
  for (int fm = 0; fm < 8; ++fm) {
#pragma unroll
    for (int reg = 0; reg < 4; ++reg) {
      int m = m0 + wr * 128 + fm * 16 + ((lane >> 4) << 2) + reg;
      if (m >= mk) continue;
      int4 mt = metaS[m - m0];
      float gi = acc[fm][0][reg] + bq[0];
      float gf = acc[fm][1][reg] + bq[1];
      float gg = acc[fm][2][reg] + bq[2];
      float go = acc[fm][3][reg] + bq[3];
      float iv = sigmoidf_(gi), fv = sigmoidf_(gf);
      float gv = tanhf_(gg), ov = sigmoidf_(go);
      float cp, hp;
      if (FIRST) { cp = 0.f; hp = 0.f; }
      else {
        cp = cst[(size_t)m * HDIM + j];
        hp = (float)hprev[(size_t)m * HDIM + j];
      }
      float cn = fv * cp + iv * gv;
      float hn = ov * tanhf_(cn);
      float hz = ZK * hp + (1.f - ZK) * hn;
      float cz = ZK * cp + (1.f - ZK) * cn;
      out[((size_t)(mt.x + k) * BATCH + mt.y) * HDIM + j] = hz;
      if (k == mt.w - 1) {
        out[segoff + ((size_t)mt.y * SEGS + mt.z) * HDIM + j] = hz;
      } else {
        hnext[(size_t)m * HDIM + j] = (f16)hz;
        cst[(size_t)m * HDIM + j] = cz;
      }
    }
  }
}

// ============ TAIL: 128x128 4-wave kernel (round-3 exact form) ============
template <bool FIRST>
__global__ void step_kernel(const f16* __restrict__ xh, const f16* __restrict__ Wc,
                            const float* __restrict__ biasp,
                            const f16* __restrict__ hprev, f16* __restrict__ hnext,
                            float* __restrict__ cst,
                            const int4* __restrict__ meta, const int* __restrict__ Mk,
                            float* __restrict__ out, int T, int k) {
  const int mk = Mk[k];
  const int m0 = blockIdx.y * 128;
  if (m0 >= mk) return;
  const int n0 = blockIdx.x * 128;

  __shared__ __align__(16) f16 At[128][64];
  __shared__ __align__(16) f16 Bt[128][64];
  __shared__ int4 metaS[128];

  const int tid = threadIdx.x;
  const int lane = tid & 63;
  const int w = tid >> 6;
  const int wr = w >> 1, wc = w & 1;

  if (tid < 128) metaS[tid] = meta[m0 + tid];

  const f16* xsrc[4];
  const f16* hsrc[4];
  const f16* wsrc[4];
#pragma unroll
  for (int i = 0; i < 4; ++i) {
    int r = m0 + w * 32 + i * 8 + (lane >> 3);
    int ra = (r < mk) ? r : 0;
    int4 mt = meta[ra];
    xsrc[i] = xh + ((size_t)(mt.x + k) * BATCH + mt.y) * IDIM;
    hsrc[i] = hprev + (size_t)ra * HDIM;
    wsrc[i] = Wc + (size_t)(n0 + w * 32 + i * 8 + (lane >> 3)) * 1024;
  }
  const int koff = (lane & 7) * 8;

  f32x4 acc[4][4];
#pragma unroll
  for (int a = 0; a < 4; ++a)
#pragma unroll
    for (int bb = 0; bb < 4; ++bb) acc[a][bb] = (f32x4){0.f, 0.f, 0.f, 0.f};

  const int KB = FIRST ? 8 : 16;
  for (int kb = 0; kb < KB; ++kb) {
    __syncthreads();
#pragma unroll
    for (int i = 0; i < 4; ++i) {
      const f16* s;
      if (FIRST) s = xsrc[i] + kb * 64 + koff;
      else       s = (kb < 8) ? (xsrc[i] + kb * 64 + koff) : (hsrc[i] + (kb - 8) * 64 + koff);
      gload16(s, &At[w * 32 + i * 8][0]);
    }
#pragma unroll
    for (int i = 0; i < 4; ++i) gload16(wsrc[i] + kb * 64 + koff, &Bt[w * 32 + i * 8][0]);
    __syncthreads();

    const int lr = lane & 15;
    const int lk = (lane >> 4) * 8;
#pragma unroll
    for (int ks = 0; ks < 2; ++ks) {
      f16x8 af[4], bfr[4];
#pragma unroll
      for (int f = 0; f < 4; ++f) af[f] = *(const f16x8*)&At[wr * 64 + f * 16 + lr][ks * 32 + lk];
#pragma unroll
      for (int f = 0; f < 4; ++f) bfr[f] = *(const f16x8*)&Bt[wc * 64 + f * 16 + lr][ks * 32 + lk];
#pragma unroll
      for (int fm = 0; fm < 4; ++fm)
#pragma unroll
        for (int fn = 0; fn < 4; ++fn)
          acc[fm][fn] = __builtin_amdgcn_mfma_f32_16x16x32_f16(af[fm], bfr[fn], acc[fm][fn], 0, 0, 0);
    }
  }

  const int r15 = lane & 15;
  float bq[4];
#pragma unroll
  for (int q = 0; q < 4; ++q) bq[q] = biasp[n0 + wc * 64 + q * 16 + r15];
  const int j = ((n0 + wc * 64) >> 6) * 16 + r15;
  const size_t segoff = (size_t)T * BATCH * HDIM + (size_t)2 * BATCH * HDIM;

#pragma unroll
  for (int fm = 0; fm < 4; ++fm) {
#pragma unroll
    for (int reg = 0; reg < 4; ++reg) {
      int m = m0 + wr * 64 + fm * 16 + ((lane >> 4) << 2) + reg;
      if (m >= mk) continue;
      int4 mt = metaS[m - m0];
      float gi = acc[fm][0][reg] + bq[0];
      float gf = acc[fm][1][reg] + bq[1];
      float gg = acc[fm][2][reg] + bq[2];
      float go = acc[fm][3][reg] + bq[3];
      float iv = sigmoidf_(gi), fv = sigmoidf_(gf);
      float gv = tanhf_(gg), ov = sigmoidf_(go);
      float cp, hp;
      if (FIRST) { cp = 0.f; hp = 0.f; }
      else {
        cp = cst[(size_t)m * HDIM + j];
        hp = (float)hprev[(size_t)m * HDIM + j];
      }
      float cn = fv * cp + iv * gv;
      float hn = ov * tanhf_(cn);
      float hz = ZK * hp + (1.f - ZK) * hn;
      float cz = ZK * cp + (1.f - ZK) * cn;
      out[((size_t)(mt.x + k) * BATCH + mt.y) * HDIM + j] = hz;
      if (k == mt.w - 1) {
        out[segoff + ((size_t)mt.y * SEGS + mt.z) * HDIM + j] = hz;
      } else {
        hnext[(size_t)m * HDIM + j] = (f16)hz;
        cst[(size_t)m * HDIM + j] = cz;
      }
    }
  }
}

extern "C" void kernel_launch(void* const* d_in, const int* in_sizes, int n_in,
                              void* d_out, int out_size, void* d_ws, size_t ws_size,
                              hipStream_t stream) {
  const float* x = (const float*)d_in[0];
  const int* durs = (const int*)d_in[1];
  const float* Wih = (const float*)d_in[2];
  const float* Whh = (const float*)d_in[3];
  const float* bih = (const float*)d_in[4];
  const float* bhh = (const float*)d_in[5];
  float* out = (float*)d_out;
  const int T = in_sizes[0] / (BATCH * IDIM);

  char* ws = (char*)d_ws;
  size_t off = 0;
  auto alloc = [&](size_t bytes) {
    void* p = ws + off;
    off = (off + bytes + 255) & ~(size_t)255;
    return p;
  };
  f16* xh     = (f16*)alloc((size_t)T * BATCH * IDIM * 2);
  f16* Wc     = (f16*)alloc((size_t)NGATE * 1024 * 2);
  float* biasp= (float*)alloc((size_t)NGATE * 4);
  f16* hst0   = (f16*)alloc((size_t)SEGS * BATCH * HDIM * 2);
  f16* hst1   = (f16*)alloc((size_t)SEGS * BATCH * HDIM * 2);
  float* cst  = (float*)alloc((size_t)SEGS * BATCH * HDIM * 4);
  int4* meta  = (int4*)alloc((size_t)SEGS * BATCH * 16);
  int* Mk     = (int*)alloc(64);
  int* mel    = (int*)alloc(64);

  prep_kernel<<<1, 64, 0, stream>>>(durs, meta, Mk, mel);
  wprep_kernel<<<NGATE, 256, 0, stream>>>(Wih, Whh, bih, bhh, Wc, biasp);
  long n8 = (long)T * BATCH * IDIM / 8;
  xconv_kernel<<<2048, 256, 0, stream>>>(x, xh, n8);
  zero_kernel<<<2048, 128, 0, stream>>>(out, mel, T, T * BATCH + 128);

  // head: k=0..7 on the 256^2 8-wave 8-phase kernel
  dim3 hgrid(8, 32);  // x: N/256, y: M/256
  step256_kernel<true><<<hgrid, 512, 0, stream>>>(xh, Wc, biasp, hst0, hst1, cst, meta, Mk, out, T, 0);
  for (int k = 1; k < 8; ++k) {
    f16* hp = (k & 1) ? hst1 : hst0;
    f16* hn = (k & 1) ? hst0 : hst1;
    step256_kernel<false><<<hgrid, 512, 0, stream>>>(xh, Wc, biasp, hp, hn, cst, meta, Mk, out, T, k);
  }
  // tail: k=8..11 on the 128^2 kernel
  dim3 sgrid(16, 64);  // x: N/128, y: M/128
  for (int k = 8; k < 12; ++k) {
    f16* hp = (k & 1) ? hst1 : hst0;
    f16* hn = (k & 1) ? hst0 : hst1;
    step_kernel<false><<<sgrid, 256, 0, stream>>>(xh, Wc, biasp, hp, hn, cst, meta, Mk, out, T, k);
  }
}

// Round 10
// 815.042 us; speedup vs baseline: 2.0957x; 1.2434x over previous
//
#include <hip/hip_runtime.h>
#include <hip/hip_fp16.h>

#define IDIM 512
#define HDIM 512
#define NGATE 2048
#define SEGS 128
#define BATCH 64
#define ZK 0.1f

typedef _Float16 f16;
typedef _Float16 f16x8 __attribute__((ext_vector_type(8)));
typedef float f32x4 __attribute__((ext_vector_type(4)));

__device__ __forceinline__ void gload16(const void* g, void* l) {
  __builtin_amdgcn_global_load_lds((const __attribute__((address_space(1))) void*)g,
                                   (__attribute__((address_space(3))) void*)l, 16, 0, 0);
}
__device__ __forceinline__ float sigmoidf_(float x) { return 1.0f / (1.0f + __expf(-x)); }
__device__ __forceinline__ float tanhf_(float x) { return 2.0f / (1.0f + __expf(-2.0f * x)) - 1.0f; }

// ---------------- prep: starts, counting-sort by dur desc, Mk, mel_len ----------------
__global__ void prep_kernel(const int* __restrict__ durs, int4* __restrict__ meta,
                            int* __restrict__ Mk, int* __restrict__ mel) {
  __shared__ int hist[16];
  __shared__ int cur[16];
  int tid = threadIdx.x;  // 64 threads, one per batch element
  if (tid < 16) hist[tid] = 0;
  __syncthreads();
  int b = tid;
  for (int s = 0; s < SEGS; ++s) atomicAdd(&hist[durs[s * BATCH + b] & 15], 1);
  __syncthreads();
  if (tid == 0) {
    int run = 0;
    for (int d = 15; d >= 0; --d) { cur[d] = run; run += hist[d]; }
    for (int kk = 0; kk < 12; ++kk) Mk[kk] = cur[kk];
  }
  __syncthreads();
  int run = 0;
  for (int s = 0; s < SEGS; ++s) {
    int d = durs[s * BATCH + b] & 15;
    int pos = atomicAdd(&cur[d], 1);
    meta[pos] = make_int4(run, b, s, d);  // start, b, s, dur
    run += d;
  }
  mel[b] = run;
}

// ---------------- W prep: permuted Wih / Whh (fp16) + bias ----------------
__global__ void wprep_kernel(const float* __restrict__ Wih, const float* __restrict__ Whh,
                             const float* __restrict__ bih, const float* __restrict__ bhh,
                             f16* __restrict__ Wihp, f16* __restrict__ Whhp,
                             float* __restrict__ biasp) {
  int n = blockIdx.x;
  int G = n >> 6, q = (n >> 4) & 3, r = n & 15;
  int orig = q * 512 + G * 16 + r;
  for (int kk = threadIdx.x; kk < 512; kk += blockDim.x) {
    Wihp[(size_t)n * 512 + kk] = (f16)Wih[(size_t)orig * 512 + kk];
    Whhp[(size_t)n * 512 + kk] = (f16)Whh[(size_t)orig * 512 + kk];
  }
  if (threadIdx.x == 0) biasp[n] = bih[orig] + bhh[orig];
}

// ---------------- x: fp32 -> fp16 ----------------
__global__ void xconv_kernel(const float* __restrict__ x, f16* __restrict__ xh, long n8) {
  long i = (long)blockIdx.x * blockDim.x + threadIdx.x;
  long stride = (long)gridDim.x * blockDim.x;
  for (; i < n8; i += stride) {
    const float4* p = (const float4*)(x + i * 8);
    float4 a = p[0], bv = p[1];
    f16x8 o;
    o[0] = (f16)a.x;  o[1] = (f16)a.y;  o[2] = (f16)a.z;  o[3] = (f16)a.w;
    o[4] = (f16)bv.x; o[5] = (f16)bv.y; o[6] = (f16)bv.z; o[7] = (f16)bv.w;
    *(f16x8*)(xh + i * 8) = o;
  }
}

// ---------------- zero invalid output rows + h + c (grid-stride) ----------------
__global__ void zero_kernel(float* __restrict__ out, const int* __restrict__ mel,
                            int T, int total) {
  int tb = T * BATCH;
  for (int bid = blockIdx.x; bid < total; bid += gridDim.x) {
    if (bid < tb) {
      int t = bid / BATCH, b = bid - t * BATCH;
      if (t < mel[b]) continue;
      float4* p = (float4*)(out + (size_t)bid * HDIM);
      p[threadIdx.x] = make_float4(0.f, 0.f, 0.f, 0.f);
    } else {
      int e = bid - tb;
      float4* p = (float4*)(out + (size_t)tb * HDIM + (size_t)e * HDIM);
      p[threadIdx.x] = make_float4(0.f, 0.f, 0.f, 0.f);
    }
  }
}

// ============ FUSED STEP: h-GEMM(k) + LSTM epilogue  ∥  shadow x-GEMM(k+1) ============
// grid (16, 128): by<64 = h-role (step k); by>=64 = x-role (xg for step k+1).
// Both roles: 128x128xK512 tile, 4 waves, 34 KB LDS -> 4 blocks/CU resident.
// Launch with k=-1 runs only the x-role (prologue computing xg(0)).
__global__ __launch_bounds__(256)
void step_fused(const f16* __restrict__ xh, const f16* __restrict__ Whhp,
                const f16* __restrict__ Wihp, const float* __restrict__ biasp,
                const f16* __restrict__ xg_cur, f16* __restrict__ xg_next,
                const f16* __restrict__ hprev, f16* __restrict__ hnext,
                float* __restrict__ cst,
                const int4* __restrict__ meta, const int* __restrict__ Mk,
                float* __restrict__ out, int T, int k) {
  __shared__ __align__(16) f16 SMEM[16384];           // 32 KB
  f16 (*At)[64] = (f16(*)[64])SMEM;                   // [128][64]
  f16 (*Bt)[64] = (f16(*)[64])(SMEM + 8192);          // [128][64]
  __shared__ int4 metaS[128];

  const int tid = threadIdx.x;
  const int lane = tid & 63;
  const int w = tid >> 6;
  const int wr = w >> 1, wc = w & 1;
  const int lrr = lane & 15;
  const int lkk = (lane >> 4) * 8;
  const int lk4 = (lane >> 4) << 2;
  const int koff = (lane & 7) * 8;
  const int n0 = blockIdx.x * 128;

  f32x4 acc[4][4];
#pragma unroll
  for (int a = 0; a < 4; ++a)
#pragma unroll
    for (int bb = 0; bb < 4; ++bb) acc[a][bb] = (f32x4){0.f, 0.f, 0.f, 0.f};

  if (blockIdx.y < 64) {
    // ================= h-role: recurrent step k =================
    if (k < 0) return;
    const int mk = Mk[k];
    const int m0 = blockIdx.y * 128;
    if (m0 >= mk) return;

    if (tid < 128) metaS[tid] = meta[m0 + tid];

    if (k > 0) {
      const f16* hsrc[4];
      const f16* wsrc[4];
#pragma unroll
      for (int i = 0; i < 4; ++i) {
        int r = m0 + w * 32 + i * 8 + (lane >> 3);
        int ra = (r < mk) ? r : 0;
        hsrc[i] = hprev + (size_t)ra * HDIM;
        wsrc[i] = Whhp + (size_t)(n0 + w * 32 + i * 8 + (lane >> 3)) * 512;
      }
      for (int kb = 0; kb < 8; ++kb) {
        __syncthreads();
#pragma unroll
        for (int i = 0; i < 4; ++i) gload16(hsrc[i] + kb * 64 + koff, &At[w * 32 + i * 8][0]);
#pragma unroll
        for (int i = 0; i < 4; ++i) gload16(wsrc[i] + kb * 64 + koff, &Bt[w * 32 + i * 8][0]);
        __syncthreads();
#pragma unroll
        for (int ks = 0; ks < 2; ++ks) {
          f16x8 af[4], bfr[4];
#pragma unroll
          for (int f = 0; f < 4; ++f) af[f] = *(const f16x8*)&At[wr * 64 + f * 16 + lrr][ks * 32 + lkk];
#pragma unroll
          for (int f = 0; f < 4; ++f) bfr[f] = *(const f16x8*)&Bt[wc * 64 + f * 16 + lrr][ks * 32 + lkk];
#pragma unroll
          for (int fm = 0; fm < 4; ++fm)
#pragma unroll
            for (int fn = 0; fn < 4; ++fn)
              acc[fm][fn] = __builtin_amdgcn_mfma_f32_16x16x32_f16(af[fm], bfr[fn], acc[fm][fn], 0, 0, 0);
        }
      }
    } else {
      __syncthreads();  // metaS visibility (no GEMM at k==0)
    }

    // ---- fused LSTM epilogue: gates = acc + xg_cur + bias ----
    float bq[4];
#pragma unroll
    for (int q = 0; q < 4; ++q) bq[q] = biasp[n0 + wc * 64 + q * 16 + lrr];
    const int nb = n0 + wc * 64 + lrr;
    const int j = ((n0 + wc * 64) >> 6) * 16 + lrr;
    const size_t segoff = (size_t)T * BATCH * HDIM + (size_t)2 * BATCH * HDIM;

#pragma unroll
    for (int fm = 0; fm < 4; ++fm) {
#pragma unroll
      for (int reg = 0; reg < 4; ++reg) {
        int m = m0 + wr * 64 + fm * 16 + lk4 + reg;
        if (m >= mk) continue;
        int4 mt = metaS[m - m0];
        const f16* xgp = xg_cur + (size_t)m * NGATE;
        float gi = acc[fm][0][reg] + (float)xgp[nb] + bq[0];
        float gf = acc[fm][1][reg] + (float)xgp[nb + 16] + bq[1];
        float gg = acc[fm][2][reg] + (float)xgp[nb + 32] + bq[2];
        float go = acc[fm][3][reg] + (float)xgp[nb + 48] + bq[3];
        float iv = sigmoidf_(gi), fv = sigmoidf_(gf);
        float gv = tanhf_(gg), ov = sigmoidf_(go);
        float cp, hp;
        if (k == 0) { cp = 0.f; hp = 0.f; }
        else {
          cp = cst[(size_t)m * HDIM + j];
          hp = (float)hprev[(size_t)m * HDIM + j];
        }
        float cn = fv * cp + iv * gv;
        float hn = ov * tanhf_(cn);
        float hz = ZK * hp + (1.f - ZK) * hn;
        float cz = ZK * cp + (1.f - ZK) * cn;
        out[((size_t)(mt.x + k) * BATCH + mt.y) * HDIM + j] = hz;
        if (k == mt.w - 1) {
          out[segoff + ((size_t)mt.y * SEGS + mt.z) * HDIM + j] = hz;
        } else {
          hnext[(size_t)m * HDIM + j] = (f16)hz;
          cst[(size_t)m * HDIM + j] = cz;
        }
      }
    }
  } else {
    // ================= x-role: xg(kt) = x_t @ Wih^T for step kt = k+1 =================
    const int kt = k + 1;
    if (kt >= 12) return;
    const int mk = Mk[kt];
    const int m0 = (blockIdx.y - 64) * 128;
    if (m0 >= mk) return;

    const f16* xsrc[4];
    const f16* wsrc[4];
#pragma unroll
    for (int i = 0; i < 4; ++i) {
      int r = m0 + w * 32 + i * 8 + (lane >> 3);
      int ra = (r < mk) ? r : 0;
      int4 mt = meta[ra];
      xsrc[i] = xh + ((size_t)(mt.x + kt) * BATCH + mt.y) * IDIM;
      wsrc[i] = Wihp + (size_t)(n0 + w * 32 + i * 8 + (lane >> 3)) * 512;
    }
    for (int kb = 0; kb < 8; ++kb) {
      __syncthreads();
#pragma unroll
      for (int i = 0; i < 4; ++i) gload16(xsrc[i] + kb * 64 + koff, &At[w * 32 + i * 8][0]);
#pragma unroll
      for (int i = 0; i < 4; ++i) gload16(wsrc[i] + kb * 64 + koff, &Bt[w * 32 + i * 8][0]);
      __syncthreads();
#pragma unroll
      for (int ks = 0; ks < 2; ++ks) {
        f16x8 af[4], bfr[4];
#pragma unroll
        for (int f = 0; f < 4; ++f) af[f] = *(const f16x8*)&At[wr * 64 + f * 16 + lrr][ks * 32 + lkk];
#pragma unroll
        for (int f = 0; f < 4; ++f) bfr[f] = *(const f16x8*)&Bt[wc * 64 + f * 16 + lrr][ks * 32 + lkk];
#pragma unroll
        for (int fm = 0; fm < 4; ++fm)
#pragma unroll
          for (int fn = 0; fn < 4; ++fn)
            acc[fm][fn] = __builtin_amdgcn_mfma_f32_16x16x32_f16(af[fm], bfr[fn], acc[fm][fn], 0, 0, 0);
      }
    }

    // ---- epilogue: LDS repack -> coalesced f16 store of xg rows ----
    __syncthreads();
    f16* SM2 = SMEM;  // [128][128]
#pragma unroll
    for (int fm = 0; fm < 4; ++fm)
#pragma unroll
      for (int reg = 0; reg < 4; ++reg) {
        int lm = wr * 64 + fm * 16 + lk4 + reg;
#pragma unroll
        for (int q = 0; q < 4; ++q)
          SM2[lm * 128 + wc * 64 + q * 16 + lrr] = (f16)acc[fm][q][reg];
      }
    __syncthreads();
#pragma unroll
    for (int i = 0; i < 8; ++i) {
      int idx = i * 256 + tid;
      int lm = idx >> 4, c = idx & 15;
      *(f16x8*)(xg_next + (size_t)(m0 + lm) * NGATE + n0 + c * 8) =
          *(const f16x8*)&SM2[lm * 128 + c * 8];
    }
  }
}

extern "C" void kernel_launch(void* const* d_in, const int* in_sizes, int n_in,
                              void* d_out, int out_size, void* d_ws, size_t ws_size,
                              hipStream_t stream) {
  const float* x = (const float*)d_in[0];
  const int* durs = (const int*)d_in[1];
  const float* Wih = (const float*)d_in[2];
  const float* Whh = (const float*)d_in[3];
  const float* bih = (const float*)d_in[4];
  const float* bhh = (const float*)d_in[5];
  float* out = (float*)d_out;
  const int T = in_sizes[0] / (BATCH * IDIM);

  char* ws = (char*)d_ws;
  size_t off = 0;
  auto alloc = [&](size_t bytes) {
    void* p = ws + off;
    off = (off + bytes + 255) & ~(size_t)255;
    return p;
  };
  f16* xh      = (f16*)alloc((size_t)T * BATCH * IDIM * 2);
  f16* Wihp    = (f16*)alloc((size_t)NGATE * 512 * 2);
  f16* Whhp    = (f16*)alloc((size_t)NGATE * 512 * 2);
  float* biasp = (float*)alloc((size_t)NGATE * 4);
  f16* xg0     = (f16*)alloc((size_t)SEGS * BATCH * NGATE * 2);  // 32 MB
  f16* xg1     = (f16*)alloc((size_t)SEGS * BATCH * NGATE * 2);  // 32 MB
  f16* hst0    = (f16*)alloc((size_t)SEGS * BATCH * HDIM * 2);
  f16* hst1    = (f16*)alloc((size_t)SEGS * BATCH * HDIM * 2);
  float* cst   = (float*)alloc((size_t)SEGS * BATCH * HDIM * 4);
  int4* meta   = (int4*)alloc((size_t)SEGS * BATCH * 16);
  int* Mk      = (int*)alloc(64);
  int* mel     = (int*)alloc(64);

  prep_kernel<<<1, 64, 0, stream>>>(durs, meta, Mk, mel);
  wprep_kernel<<<NGATE, 256, 0, stream>>>(Wih, Whh, bih, bhh, Wihp, Whhp, biasp);
  long n8 = (long)T * BATCH * IDIM / 8;
  xconv_kernel<<<2048, 256, 0, stream>>>(x, xh, n8);
  zero_kernel<<<2048, 128, 0, stream>>>(out, mel, T, T * BATCH + 128);

  dim3 grid(16, 128);
  // prologue: x-role only, computes xg(0) into xg0
  step_fused<<<grid, 256, 0, stream>>>(xh, Whhp, Wihp, biasp, xg1, xg0,
                                       hst0, hst1, cst, meta, Mk, out, T, -1);
  for (int k = 0; k < 12; ++k) {
    f16* xgc = (k & 1) ? xg1 : xg0;
    f16* xgn = (k & 1) ? xg0 : xg1;
    f16* hp = (k & 1) ? hst1 : hst0;   // step 0 writes hst1; step k reads (k&1?hst1:hst0)
    f16* hn = (k & 1) ? hst0 : hst1;
    step_fused<<<grid, 256, 0, stream>>>(xh, Whhp, Wihp, biasp, xgc, xgn,
                                         hp, hn, cst, meta, Mk, out, T, k);
  }
}